// Round 4
// baseline (90.158 us; speedup 1.0000x reference)
//
#include <hip/hip_runtime.h>

// 3D median 3x3x3, zero pad, exact. Round 4: SAME algorithm as round 3, but
// ALL state in named scalars (token-pasted macros, no local arrays, no
// pointers into locals). Evidence for this change: round-1 counters showed
// VGPR_Count=20 with >=38 floats live -> local arrays were in SCRATCH, not
// registers; every network op paid a private-memory round trip.
// Algorithm (exactness verified rounds 1-3, absmax 0.0):
//   z-sort, y-sort shared over 6-wide x window; per output, pruned x band
//   stats (19 of 27), 4x antichain sort3 exclusions (union-of-upsets rank
//   certificates), specialized round (3 CE), then window-9 forgetful
//   selection for rank 8 of 15.

#define CE(a, b) do { float _t = fminf(a, b); b = fmaxf(a, b); a = _t; } while (0)
#define SORT3(a, b, c) do { \
    float _lo = fminf(fminf(a, b), c); \
    float _hi = fmaxf(fmaxf(a, b), c); \
    float _md = __builtin_amdgcn_fmed3f(a, b, c); \
    a = _lo; b = _md; c = _hi; } while (0)
#define MIN3(a, b, c) fminf(fminf(a, b), c)
#define MAX3(a, b, c) fmaxf(fmaxf(a, b), c)
#define MED3(a, b, c) __builtin_amdgcn_fmed3f(a, b, c)

// minmax_round<0,8> / <1,7> / <2,6> spelled out on named w_0..w_8:
#define MMR08 do { CE(w_1,w_2); CE(w_3,w_4); CE(w_5,w_6); CE(w_7,w_8); \
    CE(w_0,w_1); CE(w_0,w_3); CE(w_0,w_5); CE(w_0,w_7); \
    CE(w_2,w_8); CE(w_4,w_8); CE(w_6,w_8); CE(w_1,w_8); } while (0)
#define MMR17 do { CE(w_2,w_3); CE(w_4,w_5); CE(w_6,w_7); \
    CE(w_1,w_2); CE(w_1,w_4); CE(w_1,w_6); \
    CE(w_3,w_7); CE(w_5,w_7); CE(w_2,w_7); } while (0)
#define MMR26 do { CE(w_3,w_4); CE(w_5,w_6); \
    CE(w_2,w_3); CE(w_2,w_5); CE(w_4,w_6); CE(w_3,w_6); } while (0)

#define DECLROW(R) float v##R##_0, v##R##_1, v##R##_2, v##R##_3, v##R##_4, v##R##_5;

#define LOADROW(R, DZ, DY) do { \
    const int dd = d + (DZ) - 1; \
    const bool zok = (unsigned)dd < (unsigned)D; \
    const int dc = zok ? dd : 0; \
    const int hh = h + (DY) - 1; \
    const bool hok = (unsigned)hh < (unsigned)H; \
    const int hc = hok ? hh : 0; \
    const bool ok = zok && hok; \
    const float *rowp = x + (size_t)(dc * H + hc) * W; \
    const float _l = rowp[wl]; \
    const float4 _m = *(const float4 *)(rowp + w0); \
    const float _r = rowp[wr]; \
    v##R##_0 = (ok && lval) ? _l : 0.0f; \
    v##R##_1 = ok ? _m.x : 0.0f; \
    v##R##_2 = ok ? _m.y : 0.0f; \
    v##R##_3 = ok ? _m.z : 0.0f; \
    v##R##_4 = ok ? _m.w : 0.0f; \
    v##R##_5 = (ok && rval) ? _r : 0.0f; } while (0)

// Rows R = dz*3+dy. z-sort: (y, y+3, y+6); y-sort: (3z, 3z+1, 3z+2).
#define ZSORT(C) do { SORT3(v0_##C, v3_##C, v6_##C); \
    SORT3(v1_##C, v4_##C, v7_##C); SORT3(v2_##C, v5_##C, v8_##C); } while (0)
#define YSORT(C) do { SORT3(v0_##C, v1_##C, v2_##C); \
    SORT3(v3_##C, v4_##C, v5_##C); SORT3(v6_##C, v7_##C, v8_##C); } while (0)

#define PEROUT(C0, C1, C2, RES) do { \
    float A02 = MAX3(v0_##C0, v0_##C1, v0_##C2); \
    float A11 = MED3(v1_##C0, v1_##C1, v1_##C2); \
    float A12 = MAX3(v1_##C0, v1_##C1, v1_##C2); \
    float A20 = v2_##C0, A21 = v2_##C1, A22 = v2_##C2; SORT3(A20, A21, A22); \
    float B01 = MED3(v3_##C0, v3_##C1, v3_##C2); \
    float B02 = MAX3(v3_##C0, v3_##C1, v3_##C2); \
    float B10 = v4_##C0, B11 = v4_##C1, B12 = v4_##C2; SORT3(B10, B11, B12); \
    float B20 = MIN3(v5_##C0, v5_##C1, v5_##C2); \
    float B21 = MED3(v5_##C0, v5_##C1, v5_##C2); \
    float C00 = v6_##C0, C01 = v6_##C1, C02 = v6_##C2; SORT3(C00, C01, C02); \
    float C10 = MIN3(v7_##C0, v7_##C1, v7_##C2); \
    float C11 = MED3(v7_##C0, v7_##C1, v7_##C2); \
    float C20 = MIN3(v8_##C0, v8_##C1, v8_##C2); \
    float pa = A11, pb = B01, pc = B10; SORT3(pa, pb, pc); /* pa <= med */ \
    float qa = B12, qb = B21, qc = C11; SORT3(qa, qb, qc); /* qc >= med */ \
    float ra = A02, rb = A20, rc = C00; SORT3(ra, rb, rc); /* ra <= med */ \
    float sa = A22, sb = C02, sc = C20; SORT3(sa, sb, sc); /* sc >= med */ \
    (void)pa; (void)qc; (void)ra; (void)sc; \
    CE(pb, rb);             /* pb = window min of round 1 -> discard */ \
    CE(rc, qb); CE(qb, sb); /* sb = window max of round 1 -> discard */ \
    float w_0 = rb, w_1 = pc, w_2 = B11, w_3 = qa, w_4 = rc, w_5 = qb, \
          w_6 = sa, w_7 = A12, w_8 = C10; \
    MMR08; w_0 = A21; w_8 = C01; \
    MMR08; w_0 = B02; w_8 = B20; \
    MMR08; \
    MMR17; \
    MMR26; \
    RES = MED3(w_3, w_4, w_5); } while (0)

__global__ __launch_bounds__(256) void median3d_kernel(
    const float *__restrict__ x, float *__restrict__ out) {
    const int W = 256, H = 256, D = 64;
    const int lane = threadIdx.x;   // wave spans full 256-wide x row
    const int w0 = lane << 2;       // 4 outputs: w0..w0+3
    const int h = blockIdx.y * 4 + threadIdx.y;
    const int d = blockIdx.z;
    // Clamped halo addresses (in-bounds; value cndmask'd to 0 at edges).
    const int wl = (lane == 0) ? 0 : (w0 - 1);
    const int wr = (lane == 63) ? (W - 1) : (w0 + 4);
    const bool lval = (lane != 0), rval = (lane != 63);

    DECLROW(0) DECLROW(1) DECLROW(2) DECLROW(3) DECLROW(4)
    DECLROW(5) DECLROW(6) DECLROW(7) DECLROW(8)

    LOADROW(0, 0, 0); LOADROW(1, 0, 1); LOADROW(2, 0, 2);
    LOADROW(3, 1, 0); LOADROW(4, 1, 1); LOADROW(5, 1, 2);
    LOADROW(6, 2, 0); LOADROW(7, 2, 1); LOADROW(8, 2, 2);

    ZSORT(0); ZSORT(1); ZSORT(2); ZSORT(3); ZSORT(4); ZSORT(5);
    YSORT(0); YSORT(1); YSORT(2); YSORT(3); YSORT(4); YSORT(5);

    float res0, res1, res2, res3;
    PEROUT(0, 1, 2, res0);
    PEROUT(1, 2, 3, res1);
    PEROUT(2, 3, 4, res2);
    PEROUT(3, 4, 5, res3);

    float4 r4 = make_float4(res0, res1, res2, res3);
    *(float4 *)(out + ((size_t)(d * H + h)) * W + w0) = r4;
}

extern "C" void kernel_launch(void *const *d_in, const int *in_sizes, int n_in,
                              void *d_out, int out_size, void *d_ws,
                              size_t ws_size, hipStream_t stream) {
    const float *x = (const float *)d_in[0];
    float *out = (float *)d_out;
    dim3 block(64, 4, 1);
    dim3 grid(1, 256 / 4, 64);
    median3d_kernel<<<grid, block, 0, stream>>>(x, out);
}

// Round 5
// 80.621 us; speedup vs baseline: 1.1183x; 1.1183x over previous
//
#include <hip/hip_runtime.h>

// 3D median 3x3x3, zero pad, exact. Round 5:
// - z-strip of 2 outputs/thread; y-sort done per PLANE (before z-sort) and
//   shared across the two z-windows (shear order y,z is as valid as z,y).
// - Selection rewritten on min3/med3/max3 primitives: triple-structured
//   forgetful (3 sorted triples; round = drop min&max 4 ops + reform 3 sort3)
//   finished by med9-of-3-sorted-triples = med3(max3 mins, med3 meds,
//   min3 maxes) -- verified exact via 0-1 principle.
// - Pre-exclusion antichain sort3s + band-stat pruning unchanged from R3
//   (absmax 0.0 in rounds 1-4).

#define MIN3(a, b, c) fminf(fminf(a, b), c)
#define MAX3(a, b, c) fmaxf(fmaxf(a, b), c)
#define MED3(a, b, c) __builtin_amdgcn_fmed3f(a, b, c)

__device__ __forceinline__ void sort3(float &a, float &b, float &c) {
    float lo = MIN3(a, b, c);
    float hi = MAX3(a, b, c);
    float md = MED3(a, b, c);
    a = lo; b = md; c = hi;
}

// Exact median of the 27-window given V[line=zr*3+yr][col], lines z/y sorted.
// o = first of 3 columns. Rank-10-of-19 candidates -> rank-8-of-15 after
// antichain exclusions -> triple-forgetful.
__device__ __forceinline__ float sel19(const float V[9][6], int o) {
    // Band stats (only the 19 candidate order-stats per line):
    float a0h = MAX3(V[0][o], V[0][o + 1], V[0][o + 2]);
    float a1m = MED3(V[1][o], V[1][o + 1], V[1][o + 2]);
    float a1h = MAX3(V[1][o], V[1][o + 1], V[1][o + 2]);
    float a2l = V[2][o], a2m = V[2][o + 1], a2h = V[2][o + 2];
    sort3(a2l, a2m, a2h);
    float b0m = MED3(V[3][o], V[3][o + 1], V[3][o + 2]);
    float b0h = MAX3(V[3][o], V[3][o + 1], V[3][o + 2]);
    float b1l = V[4][o], b1m = V[4][o + 1], b1h = V[4][o + 2];
    sort3(b1l, b1m, b1h);
    float b2l = MIN3(V[5][o], V[5][o + 1], V[5][o + 2]);
    float b2m = MED3(V[5][o], V[5][o + 1], V[5][o + 2]);
    float c0l = V[6][o], c0m = V[6][o + 1], c0h = V[6][o + 2];
    sort3(c0l, c0m, c0h);
    float c1l = MIN3(V[7][o], V[7][o + 1], V[7][o + 2]);
    float c1m = MED3(V[7][o], V[7][o + 1], V[7][o + 2]);
    float c2l = MIN3(V[8][o], V[8][o + 1], V[8][o + 2]);

    // Antichain pre-exclusions (rank certificates, validated R3/R4):
    float pa = a1m, pb = b0m, pc = b1l; sort3(pa, pb, pc);  // pa <= med
    float qa = b1h, qb = b2m, qc = c1m; sort3(qa, qb, qc);  // qc >= med
    float ra = a0h, rb = a2l, rc = c0l; sort3(ra, rb, rc);  // ra <= med
    float sa = a2h, sb = c0h, sc = c2l; sort3(sa, sb, sc);  // sc >= med
    (void)pa; (void)qc; (void)ra; (void)sc;

    // 15 survivors, rank 8. Window = 3 sorted triples.
    // T1=(pb,pc,b1m) sorted for free: pb<=pc (sort) and pc<=b1m (chain:
    // a1m,b0m,b1l are all <= b1m by line/axis dominance).
    float t1l = pb, t1m = pc, t1h = b1m;
    float t2l = rb, t2m = rc, t2h = a1h; sort3(t2l, t2m, t2h);
    float t3l = sa, t3m = sb, t3h = c1l; sort3(t3l, t3m, t3h);

    // Round 1: drop window min&max, insert qa,qb.
    {
        float lam1 = MED3(t1l, t2l, t3l), lam2 = MAX3(t1l, t2l, t3l);
        float eta1 = MIN3(t1h, t2h, t3h), eta2 = MED3(t1h, t2h, t3h);
        float mu1 = t1m, mu2 = t2m, mu3 = t3m;
        t1l = lam1; t1m = lam2; t1h = qa; sort3(t1l, t1m, t1h);
        t2l = mu1;  t2m = mu2;  t2h = mu3; sort3(t2l, t2m, t2h);
        t3l = eta1; t3m = eta2; t3h = qb; sort3(t3l, t3m, t3h);
    }
    // Round 2: insert a2m, c0m.
    {
        float lam1 = MED3(t1l, t2l, t3l), lam2 = MAX3(t1l, t2l, t3l);
        float eta1 = MIN3(t1h, t2h, t3h), eta2 = MED3(t1h, t2h, t3h);
        float mu1 = t1m, mu2 = t2m, mu3 = t3m;
        t1l = lam1; t1m = lam2; t1h = a2m; sort3(t1l, t1m, t1h);
        t2l = mu1;  t2m = mu2;  t2h = mu3; sort3(t2l, t2m, t2h);
        t3l = eta1; t3m = eta2; t3h = c0m; sort3(t3l, t3m, t3h);
    }
    // Round 3: insert b0h, b2l; then med9 of 3 sorted triples.
    {
        float lam1 = MED3(t1l, t2l, t3l), lam2 = MAX3(t1l, t2l, t3l);
        float eta1 = MIN3(t1h, t2h, t3h), eta2 = MED3(t1h, t2h, t3h);
        float mu1 = t1m, mu2 = t2m, mu3 = t3m;
        t1l = lam1; t1m = lam2; t1h = b0h; sort3(t1l, t1m, t1h);
        t2l = mu1;  t2m = mu2;  t2h = mu3; sort3(t2l, t2m, t2h);
        t3l = eta1; t3m = eta2; t3h = b2l; sort3(t3l, t3m, t3h);
    }
    return MED3(MAX3(t1l, t2l, t3l), MED3(t1m, t2m, t3m),
                MIN3(t1h, t2h, t3h));
}

__global__ __launch_bounds__(256) void median3d_kernel(
    const float *__restrict__ x, float *__restrict__ out) {
    const int W = 256, H = 256, D = 64;
    const int lane = threadIdx.x;   // wave spans full 256-wide x row
    const int w0 = lane << 2;       // 4 x-outputs
    const int h = blockIdx.y * 4 + threadIdx.y;
    const int d0 = blockIdx.z * 2;  // 2 z-outputs: d0, d0+1
    const int wl = (lane == 0) ? 0 : (w0 - 1);
    const int wr = (lane == 63) ? (W - 1) : (w0 + 4);
    const bool lval = (lane != 0), rval = (lane != 63);

    // Per-plane y-sorted stats: Y[plane][ystat][col], planes d0-1..d0+2.
    float Y[4][3][6];
#pragma unroll
    for (int p = 0; p < 4; ++p) {
        const int dd = d0 + p - 1;
        const bool zok = (unsigned)dd < (unsigned)D;
        const int dc = zok ? dd : 0;
        float r[3][6];
#pragma unroll
        for (int dy = 0; dy < 3; ++dy) {
            const int hh = h + dy - 1;
            const bool hok = (unsigned)hh < (unsigned)H;
            const int hc = hok ? hh : 0;
            const bool ok = zok && hok;
            const float *rowp = x + (size_t)(dc * H + hc) * W;
            const float l = rowp[wl];
            const float4 m = *(const float4 *)(rowp + w0);
            const float rr = rowp[wr];
            r[dy][0] = (ok && lval) ? l : 0.0f;
            r[dy][1] = ok ? m.x : 0.0f;
            r[dy][2] = ok ? m.y : 0.0f;
            r[dy][3] = ok ? m.z : 0.0f;
            r[dy][4] = ok ? m.w : 0.0f;
            r[dy][5] = (ok && rval) ? rr : 0.0f;
        }
#pragma unroll
        for (int c = 0; c < 6; ++c) {
            sort3(r[0][c], r[1][c], r[2][c]);
            Y[p][0][c] = r[0][c];
            Y[p][1][c] = r[1][c];
            Y[p][2][c] = r[2][c];
        }
    }

#pragma unroll
    for (int zo = 0; zo < 2; ++zo) {
        // z-sort the y-stats across planes zo..zo+2 -> monotone (z,y) lines.
        float V[9][6];
#pragma unroll
        for (int yr = 0; yr < 3; ++yr)
#pragma unroll
            for (int c = 0; c < 6; ++c) {
                float a = Y[zo][yr][c];
                float b = Y[zo + 1][yr][c];
                float cc = Y[zo + 2][yr][c];
                sort3(a, b, cc);
                V[0 + yr][c] = a;
                V[3 + yr][c] = b;
                V[6 + yr][c] = cc;
            }
        float4 r4;
        r4.x = sel19(V, 0);
        r4.y = sel19(V, 1);
        r4.z = sel19(V, 2);
        r4.w = sel19(V, 3);
        *(float4 *)(out + (size_t)((d0 + zo) * H + h) * W + w0) = r4;
    }
}

extern "C" void kernel_launch(void *const *d_in, const int *in_sizes, int n_in,
                              void *d_out, int out_size, void *d_ws,
                              size_t ws_size, hipStream_t stream) {
    const float *x = (const float *)d_in[0];
    float *out = (float *)d_out;
    dim3 block(64, 4, 1);
    dim3 grid(1, 256 / 4, 64 / 2);
    median3d_kernel<<<grid, block, 0, stream>>>(x, out);
}